// Round 18
// baseline (61.950 us; speedup 1.0000x reference)
//
#include <hip/hip_runtime.h>
#include <math.h>

// MaxYager2d: out[b,f,si,sj] = max(0, 1 - (min_{c,kh,kw} A[b,c,si+kh,sj+kw] + BW[c,kh,kw,f])^(2/3))
// A = (1-x)^1.5, BW = (1-w)^1.5. Max over J commutes with the monotone-
// decreasing Yager combine -> tropical min-plus 3x3 conv.
//
// r18 = r14 (best: wave = 2f x 2rows x 64cols, half8 A, broadcast-b128 B,
// grid 256 = b x pair x fh, 512 thr) + split-q ASYNC staging:
//   stage B + A(q=0,1) | barrier | issue A(q=2,3) loads -> regs (use
//   deferred, vmcnt waits after compute) | compute q=0,1 | yg+ds_write
//   q=2,3 | barrier | compute q=2,3.
// Hides the second half of A-staging's global latency under q01 compute;
// first barrier arrives after half the staging. ds_writes (q2,3) disjoint
// from q01 reads. __launch_bounds__(512,4): 128-reg cap, ~95 live, no
// spill, 2 blocks/CU. Arithmetic byte-identical -> absmax 0.00390625.

#define CIN  32
#define FOUT 32
#define KS   3
#define HW   66
#define SS   64
#define NB   4

typedef _Float16 half2_t __attribute__((ext_vector_type(2)));
typedef _Float16 half8_t __attribute__((ext_vector_type(8)));

static __device__ __forceinline__ _Float16 yg(float v) {
    float t = 1.0f - v;
    return (_Float16)(t * sqrtf(t));   // (1-v)^1.5
}

union bv8 {
    half8_t v8;
    half2_t v2[4];
};

typedef __align__(16) half8_t ldsA_t[4][4][68];
typedef __align__(16) half2_t ldsB_t[16][148];

static __device__ __forceinline__ void compute_q(
    int q, int lane, int f0, const ldsA_t& ldsA, const ldsB_t& ldsB,
    half2_t acc[2][2][2])
{
    half8_t a[4][KS];
#pragma unroll
    for (int rr = 0; rr < 4; ++rr)
#pragma unroll
        for (int kw = 0; kw < KS; ++kw)
            a[rr][kw] = ldsA[q][rr][lane + kw];
#pragma unroll
    for (int t = 0; t < 9; ++t) {
        const int kr = t / 3, kw = t % 3;
        bv8 B0, B1;                       // wave-uniform broadcast b128
        B0.v8 = *(const half8_t*)&ldsB[f0][t * 16 + 4 * q];
        B1.v8 = *(const half8_t*)&ldsB[f0 + 1][t * 16 + 4 * q];
#pragma unroll
        for (int r = 0; r < 2; ++r) {
            bv8 av; av.v8 = a[kr + r][kw];
#pragma unroll
            for (int c4 = 0; c4 < 4; ++c4) {
                half2_t s0 = av.v2[c4] + B0.v2[c4];
                half2_t s1 = av.v2[c4] + B1.v2[c4];
                acc[r][0][c4 & 1] = __builtin_elementwise_min(acc[r][0][c4 & 1], s0);
                acc[r][1][c4 & 1] = __builtin_elementwise_min(acc[r][1][c4 & 1], s1);
            }
        }
    }
}

__global__ __launch_bounds__(512, 4) void yager_one(
    const float* __restrict__ x, const float* __restrict__ w,
    float* __restrict__ out)
{
    __shared__ ldsA_t ldsA;   // 17.4 KB [q(8ch)][row][col]
    __shared__ ldsB_t ldsB;   // 9.5 KB  [fi][t*16+4q+c4] (pad 4)

    const int tid  = threadIdx.x;
    const int fh   = blockIdx.x & 1;          // f-half
    const int pair = (blockIdx.x >> 1) & 31;  // output row pair
    const int b    = blockIdx.x >> 6;

    // --- stage B (this block's 16 f): 4608 elems, 9/thread, coalesced reads.
#pragma unroll
    for (int k = 0; k < 9; ++k) {
        int i  = tid + k * 512;
        int fi = i & 15;
        int j  = i >> 4;                      // c*9 + t
        int c  = j / 9;
        int t  = j - 9 * c;
        float v = w[j * FOUT + fh * 16 + fi];
        ((_Float16*)ldsB)[fi * 296 + t * 32 + c] = yg(v);
    }

    // --- stage A for q = 0,1 (528 half8 slots).
    for (int i = tid; i < 2 * 4 * HW; i += 512) {
        int q   = i / (4 * HW);
        int r   = i - q * (4 * HW);
        int row = r / HW;
        int col = r - row * HW;
        const float* xp = x + (((size_t)b * CIN + 8 * q) * HW + 2 * pair + row) * HW + col;
        half8_t v;
#pragma unroll
        for (int k = 0; k < 8; ++k)
            v[k] = yg(xp[(size_t)k * HW * HW]);
        ldsA[q][row][col] = v;
    }
    __syncthreads();

    const int lane = tid & 63;                                  // output col
    const int wv   = __builtin_amdgcn_readfirstlane(tid >> 6);  // 0..7
    const int f0   = wv * 2;                                    // local f pair

    // --- issue A-stage loads for q = 2,3 round-1 (slot = tid): uses deferred.
    float pre[8];
    {
        const int i   = tid;                  // 512 < 528 slots
        const int q   = 2 + i / (4 * HW);
        const int r   = i % (4 * HW);
        const int row = r / HW;
        const int col = r % HW;
        const float* xp = x + (((size_t)b * CIN + 8 * q) * HW + 2 * pair + row) * HW + col;
#pragma unroll
        for (int k = 0; k < 8; ++k)
            pre[k] = xp[(size_t)k * HW * HW];
    }

    half2_t acc[2][2][2];
#pragma unroll
    for (int r = 0; r < 2; ++r)
#pragma unroll
        for (int f = 0; f < 2; ++f)
#pragma unroll
            for (int p = 0; p < 2; ++p) {
                half2_t z; z.x = (_Float16)4.0f; z.y = (_Float16)4.0f;
                acc[r][f][p] = z;
            }

    // --- compute q = 0,1 (loads above stay in flight underneath)
    compute_q(0, lane, f0, ldsA, ldsB, acc);
    compute_q(1, lane, f0, ldsA, ldsB, acc);

    // --- finish A-stage q = 2,3: convert + write round-1, then 16-slot tail.
    {
        const int i   = tid;
        const int q   = 2 + i / (4 * HW);
        const int r   = i % (4 * HW);
        const int row = r / HW;
        const int col = r % HW;
        half8_t v;
#pragma unroll
        for (int k = 0; k < 8; ++k)
            v[k] = yg(pre[k]);
        ldsA[q][row][col] = v;
    }
    if (tid < 2 * 4 * HW - 512) {
        const int i   = tid + 512;
        const int q   = 2 + i / (4 * HW);
        const int r   = i % (4 * HW);
        const int row = r / HW;
        const int col = r % HW;
        const float* xp = x + (((size_t)b * CIN + 8 * q) * HW + 2 * pair + row) * HW + col;
        half8_t v;
#pragma unroll
        for (int k = 0; k < 8; ++k)
            v[k] = yg(xp[(size_t)k * HW * HW]);
        ldsA[q][row][col] = v;
    }
    __syncthreads();

    // --- compute q = 2,3
    compute_q(2, lane, f0, ldsA, ldsB, acc);
    compute_q(3, lane, f0, ldsA, ldsB, acc);

#pragma unroll
    for (int r = 0; r < 2; ++r)
#pragma unroll
        for (int f = 0; f < 2; ++f) {
            half2_t M = __builtin_elementwise_min(acc[r][f][0], acc[r][f][1]);
            float m = fminf((float)M.x, (float)M.y);
            float rv = 1.0f - exp2f(0.6666666667f * log2f(m));
            out[(((size_t)b * FOUT + fh * 16 + f0 + f) * SS + 2 * pair + r) * SS + lane]
                = fmaxf(rv, 0.0f);
        }
}

extern "C" void kernel_launch(void* const* d_in, const int* in_sizes, int n_in,
                              void* d_out, int out_size, void* d_ws, size_t ws_size,
                              hipStream_t stream)
{
    const float* x = (const float*)d_in[0];   // [4,32,66,66] f32
    const float* w = (const float*)d_in[1];   // [288,32] f32
    float* out = (float*)d_out;               // [4,32,64,64] f32
    (void)d_ws; (void)ws_size;

    yager_one<<<NB * 32 * 2, 512, 0, stream>>>(x, w, out);
}

// Round 19
// 14.283 us; speedup vs baseline: 4.3375x; 4.3375x over previous
//
#include <hip/hip_runtime.h>
#include <math.h>

// MaxYager2d: out[b,f,si,sj] = max(0, 1 - (min_{c,kh,kw} A[b,c,si+kh,sj+kw] + BW[c,kh,kw,f])^(2/3))
// A = (1-x)^1.5, BW = (1-w)^1.5. Max over J commutes with the monotone-
// decreasing Yager combine -> tropical min-plus 3x3 conv.
//
// r19 = r14 byte-identical body + amdgpu_waves_per_eu(4,4).
// Root cause of the session's spill pattern (r10/r13/r18: VGPR=64 + 100MB+
// scratch FETCH/WRITE): the AMDGPU backend derives its occupancy TARGET from
// LDS-allowed blocks/CU (27KB -> 40 waves -> clamps 32/CU = 8/EU = 64-reg
// budget) and SPILLS to reach it, regardless of the launch_bounds floor.
// Pinning waves_per_eu(4,4) sets a 128-reg budget: the ~70-reg live set
// (a-tile 48 + acc 8 + B 8 + addr) fits with scheduler slack, no spill,
// 2 blocks/CU = r14's intended operating point.
//
//  - wave = 2f x 2rows x 64cols; A packed half8 (8ch/slot, b128 reads);
//    B wave-uniform broadcast b128; 48 A + 72 B LDS reads per 256 outputs.
//  - grid 256 = b(4) x pair(32) x fh(2), 512 thr = 8 waves.
//  - ldsB fi-stride 296 halfs (592 B): scatter-writes 2-way (free);
//    b128 reads 16B-aligned.
// Arithmetic identical to r14 -> absmax 0.00390625 unchanged.

#define CIN  32
#define FOUT 32
#define KS   3
#define HW   66
#define SS   64
#define NB   4

typedef _Float16 half2_t __attribute__((ext_vector_type(2)));
typedef _Float16 half8_t __attribute__((ext_vector_type(8)));

static __device__ __forceinline__ _Float16 yg(float v) {
    float t = 1.0f - v;
    return (_Float16)(t * sqrtf(t));   // (1-v)^1.5
}

union bv8 {
    half8_t v8;
    half2_t v2[4];
};

__global__ __launch_bounds__(512)
__attribute__((amdgpu_waves_per_eu(4, 4)))
void yager_one(
    const float* __restrict__ x, const float* __restrict__ w,
    float* __restrict__ out)
{
    __shared__ __align__(16) half8_t ldsA[4][4][68];   // 17.4 KB [q(8ch)][row][col]
    __shared__ __align__(16) half2_t ldsB[16][148];    // 9.5 KB  [fi][t*16+4q+c4] (pad 4)

    const int tid  = threadIdx.x;
    const int fh   = blockIdx.x & 1;          // f-half
    const int pair = (blockIdx.x >> 1) & 31;  // output row pair
    const int b    = blockIdx.x >> 6;

    // --- stage B (this block's 16 f): 4608 elems, 9/thread, coalesced reads.
    // Write f16 at fi*296 + t*32 + c halfs: fi-stride 592 B -> 2-way (free).
#pragma unroll
    for (int k = 0; k < 9; ++k) {
        int i  = tid + k * 512;
        int fi = i & 15;
        int j  = i >> 4;                      // c*9 + t, 0..287
        int c  = j / 9;
        int t  = j - 9 * c;
        float v = w[j * FOUT + fh * 16 + fi];
        ((_Float16*)ldsB)[fi * 296 + t * 32 + c] = yg(v);
    }

    // --- stage A: input rows 2p..2p+3, channels as half8 slots q=0..3.
    for (int i = tid; i < 4 * 4 * HW; i += 512) {
        int q   = i / (4 * HW);
        int r   = i - q * (4 * HW);
        int row = r / HW;
        int col = r - row * HW;
        const float* xp = x + (((size_t)b * CIN + 8 * q) * HW + 2 * pair + row) * HW + col;
        half8_t v;
#pragma unroll
        for (int k = 0; k < 8; ++k)
            v[k] = yg(xp[(size_t)k * HW * HW]);
        ldsA[q][row][col] = v;
    }
    __syncthreads();

    const int lane = tid & 63;                                  // output col
    const int wv   = __builtin_amdgcn_readfirstlane(tid >> 6);  // 0..7
    const int f0   = wv * 2;                                    // local f pair

    // acc[r][f][parity] as 8 independent half2 min-chains
    half2_t acc[2][2][2];
#pragma unroll
    for (int r = 0; r < 2; ++r)
#pragma unroll
        for (int f = 0; f < 2; ++f)
#pragma unroll
            for (int p = 0; p < 2; ++p) {
                half2_t z; z.x = (_Float16)4.0f; z.y = (_Float16)4.0f;
                acc[r][f][p] = z;
            }

#pragma unroll
    for (int q = 0; q < 4; ++q) {
        // A tile: 4 LDS rows x 3 kw, serves both output rows
        half8_t a[4][KS];
#pragma unroll
        for (int rr = 0; rr < 4; ++rr)
#pragma unroll
            for (int kw = 0; kw < KS; ++kw)
                a[rr][kw] = ldsA[q][rr][lane + kw];
#pragma unroll
        for (int t = 0; t < 9; ++t) {
            const int kr = t / 3, kw = t % 3;
            bv8 B0, B1;                       // wave-uniform broadcast b128
            B0.v8 = *(const half8_t*)&ldsB[f0][t * 16 + 4 * q];
            B1.v8 = *(const half8_t*)&ldsB[f0 + 1][t * 16 + 4 * q];
#pragma unroll
            for (int r = 0; r < 2; ++r) {
                bv8 av; av.v8 = a[kr + r][kw];
#pragma unroll
                for (int c4 = 0; c4 < 4; ++c4) {
                    half2_t s0 = av.v2[c4] + B0.v2[c4];
                    half2_t s1 = av.v2[c4] + B1.v2[c4];
                    acc[r][0][c4 & 1] = __builtin_elementwise_min(acc[r][0][c4 & 1], s0);
                    acc[r][1][c4 & 1] = __builtin_elementwise_min(acc[r][1][c4 & 1], s1);
                }
            }
        }
    }

#pragma unroll
    for (int r = 0; r < 2; ++r)
#pragma unroll
        for (int f = 0; f < 2; ++f) {
            half2_t M = __builtin_elementwise_min(acc[r][f][0], acc[r][f][1]);
            float m = fminf((float)M.x, (float)M.y);
            float rv = 1.0f - exp2f(0.6666666667f * log2f(m));
            out[(((size_t)b * FOUT + fh * 16 + f0 + f) * SS + 2 * pair + r) * SS + lane]
                = fmaxf(rv, 0.0f);
        }
}

extern "C" void kernel_launch(void* const* d_in, const int* in_sizes, int n_in,
                              void* d_out, int out_size, void* d_ws, size_t ws_size,
                              hipStream_t stream)
{
    const float* x = (const float*)d_in[0];   // [4,32,66,66] f32
    const float* w = (const float*)d_in[1];   // [288,32] f32
    float* out = (float*)d_out;               // [4,32,64,64] f32
    (void)d_ws; (void)ws_size;

    yager_one<<<NB * 32 * 2, 512, 0, stream>>>(x, w, out);
}